// Round 7
// baseline (45.554 us; speedup 1.0000x reference)
//
#include <hip/hip_runtime.h>
#include <math.h>

#define NQ_     14
#define DIM_    16384
#define NB      256
#define NLAYERS 3
#define NPAIR   13
#define NT      1024

__device__ __forceinline__ float2 cmul(float2 a, float2 b) {
    return make_float2(a.x*b.x - a.y*b.y, a.x*b.y + a.y*b.x);
}

__device__ __forceinline__ void g2(float2& a0, float2& a1,
        float2 u00, float2 u01, float2 u10, float2 u11) {
    float2 b0, b1;
    b0.x = u00.x*a0.x - u00.y*a0.y + u01.x*a1.x - u01.y*a1.y;
    b0.y = u00.x*a0.y + u00.y*a0.x + u01.x*a1.y + u01.y*a1.x;
    b1.x = u10.x*a0.x - u10.y*a0.y + u11.x*a1.x - u11.y*a1.y;
    b1.y = u10.x*a0.y + u10.y*a0.x + u11.x*a1.y + u11.y*a1.x;
    a0 = b0; a1 = b1;
}

#define GATE_BIT(RB, Uptr) do { \
    float2 u00 = (Uptr)[0], u01 = (Uptr)[1], u10 = (Uptr)[2], u11 = (Uptr)[3]; \
    _Pragma("unroll") \
    for (int j = 0; j < 16; ++j) \
        if (!((j >> (RB)) & 1)) g2(a[j], a[j | (1 << (RB))], u00, u01, u10, u11); \
} while (0)

// X/Y measurement only (Z handled by the s_GL/s_GH sweep in the final pass).
#define MEASW(RB, WEXPR) do { float xr = 0.f; \
    _Pragma("unroll") for (int j = 0; j < 16; ++j) { \
        if (!((j >> (RB)) & 1)) { \
            int j1 = j | (1 << (RB)); \
            float cr = a[j].x*a[j1].x + a[j].y*a[j1].y; \
            float ci = a[j].x*a[j1].y - a[j].y*a[j1].x; \
            float2 w = (WEXPR); \
            xr += w.x * cr - w.y * ci; \
        } } \
    acc += xr; } while (0)

__global__ __launch_bounds__(NT, 4) void pqc_kernel(
    const float* __restrict__ x,     // (256, 28)
    const float* __restrict__ psq,   // (3, 2, 14, 3)
    const float* __restrict__ p2q,   // (3, 196)
    const float* __restrict__ penc,  // (3, 196)
    const float* __restrict__ pcl,   // (14,)
    float* __restrict__ out)         // (256,)
{
    __shared__ __align__(16) float2 s_amp[DIM_];   // 128 KiB state
    __shared__ float2 s_U[4][NQ_][4];              // merged gate sets
    __shared__ float2 s_C0[2][128];                // diag cis (layers 0,1; low 7 xor-bits)
    __shared__ float2 s_C1[2][64];                 // diag cis (layers 0,1; high bits, -S/2 folded)
    __shared__ float2 s_WE[NQ_][4];                // 2*W_bp*cis(dphi(s)), s=(k_{bp+1}<<1)|k_{bp-1}
    __shared__ float  s_GL[128];                   // gamma Z-weight, low 7 bits
    __shared__ float  s_GH[128];                   // gamma Z-weight, high 7 bits (Cg folded)
    __shared__ float  s_theta[NLAYERS][NPAIR];
    __shared__ float  s_red[16];

    const int n = blockIdx.x;
    const int t = threadIdx.x;

    // ---------- phase 1: theta + merged gate matrices ----------
    if (t < NLAYERS * NPAIR) {
        int l = t / NPAIR, p = t - l * NPAIR;
        const float* xr = x + n * 28;
        float feat = xr[2*p] * xr[2*p+2] + xr[2*p+1] * xr[2*p+3];
        int pf = 15 * p + 1;
        s_theta[l][p] = p2q[l*196 + pf] + penc[l*196 + pf] * feat;
    } else if (t >= 64 && t < 64 + 4 * NQ_) {
        int j = t - 64;
        int set = j / NQ_;
        int q = j - set * NQ_;
        auto build = [&](int l, int s, float2 Uo[4]) {
            const float* a = psq + ((l * 2 + s) * NQ_ + q) * 3;
            float phi = a[0], th = a[1], om = a[2];
            float sh, ch; sincosf(0.5f * th, &sh, &ch);
            float sa, ca; sincosf(0.5f * (phi + om), &sa, &ca);
            float sb, cb; sincosf(0.5f * (phi - om), &sb, &cb);
            Uo[0] = make_float2( ch * ca, -ch * sa);
            Uo[1] = make_float2(-sh * cb, -sh * sb);
            Uo[2] = make_float2( sh * cb, -sh * sb);
            Uo[3] = make_float2( ch * ca,  ch * sa);
        };
        float2 M[4];
        if (set == 0) {
            build(0, 0, M);
        } else if (set == 3) {
            build(2, 1, M);
        } else {
            float2 A[4], Bm[4];
            build(set, 0, A);        // second
            build(set - 1, 1, Bm);   // first
            M[0].x = A[0].x*Bm[0].x - A[0].y*Bm[0].y + A[1].x*Bm[2].x - A[1].y*Bm[2].y;
            M[0].y = A[0].x*Bm[0].y + A[0].y*Bm[0].x + A[1].x*Bm[2].y + A[1].y*Bm[2].x;
            M[1].x = A[0].x*Bm[1].x - A[0].y*Bm[1].y + A[1].x*Bm[3].x - A[1].y*Bm[3].y;
            M[1].y = A[0].x*Bm[1].y + A[0].y*Bm[1].x + A[1].x*Bm[3].y + A[1].y*Bm[3].x;
            M[2].x = A[2].x*Bm[0].x - A[2].y*Bm[0].y + A[3].x*Bm[2].x - A[3].y*Bm[2].y;
            M[2].y = A[2].x*Bm[0].y + A[2].y*Bm[0].x + A[3].x*Bm[2].y + A[3].y*Bm[2].x;
            M[3].x = A[2].x*Bm[1].x - A[2].y*Bm[1].y + A[3].x*Bm[3].x - A[3].y*Bm[3].y;
            M[3].y = A[2].x*Bm[1].y + A[2].y*Bm[1].x + A[3].x*Bm[3].y + A[3].y*Bm[3].x;
        }
        #pragma unroll
        for (int e = 0; e < 4; ++e) s_U[set][q][e] = M[e];
    }
    __syncthreads();

    // ---------- phase 2: diag cis tables + observable tables ----------
    if (t < 256) {
        int l = t >> 7, i = t & 127;
        float v = 0.0f;
        #pragma unroll
        for (int b = 0; b < 7; ++b)
            if ((i >> b) & 1) v += s_theta[l][12 - b];
        float sn, cs; sincosf(v, &sn, &cs);
        s_C0[l][i] = make_float2(cs, sn);
    } else if (t < 384) {
        int j = t - 256;
        int l = j >> 6, h = j & 63;
        float S = 0.0f;
        #pragma unroll
        for (int p = 0; p < NPAIR; ++p) S += s_theta[l][p];
        float v = -0.5f * S;
        #pragma unroll
        for (int b = 7; b < 13; ++b)
            if ((h >> (b - 7)) & 1) v += s_theta[l][12 - b];
        float sn, cs; sincosf(v, &sn, &cs);
        s_C1[l][h] = make_float2(cs, sn);
    } else if (t < 440) {
        // WE[bp][s] = 2 * W_bp * cis(dphi)
        int idx = t - 384, bp = idx >> 2, s = idx & 3;
        int q = 13 - bp;
        float2 v00 = s_U[3][q][0], v01 = s_U[3][q][1];
        float2 v10 = s_U[3][q][2], v11 = s_U[3][q][3];
        float cz = pcl[q], cx = pcl[bp];
        float t1x = (v00.x*v01.x + v00.y*v01.y) - (v10.x*v11.x + v10.y*v11.y);
        float t1y = (v00.x*v01.y - v00.y*v01.x) - (v10.x*v11.y - v10.y*v11.x);
        float t2x = (v00.x*v11.x + v00.y*v11.y) + (v10.x*v01.x + v10.y*v01.y);
        float t2y = (v00.x*v11.y - v00.y*v11.x) + (v10.x*v01.y - v10.y*v01.x);
        float Wx = cz*t1x + cx*t2x, Wy = cz*t1y + cx*t2y;
        float tha = (bp <= 12) ? s_theta[2][12 - bp] : 0.f;
        float thb = (bp >= 1)  ? s_theta[2][13 - bp] : 0.f;
        float dphi = tha * (1.f - 2.f*((s >> 1) & 1)) + thb * (1.f - 2.f*(s & 1));
        float sn, cs; sincosf(dphi, &sn, &cs);
        s_WE[bp][s] = make_float2(2.f*(Wx*cs - Wy*sn), 2.f*(Wx*sn + Wy*cs));
    } else if (t >= 464 && t < 592) {
        // GL[i] = sum_{b<7, bit set} gamma_b
        int i = t - 464;
        float v = 0.f;
        #pragma unroll
        for (int b = 0; b < 7; ++b)
            if ((i >> b) & 1) {
                int q = 13 - b;
                float2 v00 = s_U[3][q][0], v10 = s_U[3][q][2];
                v += pcl[q] * ((v00.x*v00.x + v00.y*v00.y) - (v10.x*v10.x + v10.y*v10.y))
                   + 2.f*pcl[b] * (v00.x*v10.x + v00.y*v10.y);
            }
        s_GL[i] = v;
    } else if (t >= 592 && t < 720) {
        // GH[h] = sum_{b<7} gamma_b + sum_{b>=7} gamma_b * (1-2*bit)
        int h = t - 592;
        float v = 0.f;
        #pragma unroll
        for (int b = 0; b < 14; ++b) {
            int q = 13 - b;
            float2 v00 = s_U[3][q][0], v10 = s_U[3][q][2];
            float g = pcl[q] * ((v00.x*v00.x + v00.y*v00.y) - (v10.x*v10.x + v10.y*v10.y))
                    + 2.f*pcl[b] * (v00.x*v10.x + v00.y*v10.y);
            v += (b >= 7 && ((h >> (b - 7)) & 1)) ? -g : g;
        }
        s_GH[h] = v;
    }
    __syncthreads();

    float2 a[16];
    float acc = 0.0f;

    // ---- layout pointer setup (XOR-swizzle folded: uniform/static per access) ----
#define SETUP_A() int axorA = (t & 7) << 1; float2* pA[8]; \
    _Pragma("unroll") for (int c = 0; c < 8; ++c) pA[c] = s_amp + ((t << 4) | ((2*c) ^ axorA));
#define LOADP_A() do { _Pragma("unroll") for (int c = 0; c < 8; ++c) { \
        float4 v = *(const float4*)pA[c]; \
        a[2*c] = make_float2(v.x, v.y); a[2*c+1] = make_float2(v.z, v.w); } } while (0)
#define STOREP_A() do { _Pragma("unroll") for (int c = 0; c < 8; ++c) \
        *(float4*)pA[c] = make_float4(a[2*c].x, a[2*c].y, a[2*c+1].x, a[2*c+1].y); } while (0)

#define SETUP_B() float2* pB[8]; { int bb = ((t >> 4) << 8) | (t & 15); \
    _Pragma("unroll") for (int g = 0; g < 8; ++g) pB[g] = s_amp + (bb ^ (g << 1)); }
#define LOADP_B() do { _Pragma("unroll") for (int j = 0; j < 16; ++j) a[j] = pB[j & 7][j << 4]; } while (0)
#define STOREP_B() do { _Pragma("unroll") for (int j = 0; j < 16; ++j) pB[j & 7][j << 4] = a[j]; } while (0)

#define SETUP_C() float2* pC = s_amp + (((((t >> 8) << 12) | (t & 255))) ^ (((t >> 4) & 7) << 1));
#define LOADP_C() do { _Pragma("unroll") for (int j = 0; j < 16; ++j) a[j] = pC[j << 8]; } while (0)
#define STOREP_C() do { _Pragma("unroll") for (int j = 0; j < 16; ++j) pC[j << 8] = a[j]; } while (0)

#define SETUP_D() int dxorD = ((t >> 2) & 7) << 1; \
    float2* pD0 = s_amp + (((t << 2) | 0) ^ dxorD); \
    float2* pD1 = s_amp + (((t << 2) | 2) ^ dxorD);
#define LOADP_D() do { _Pragma("unroll") for (int jh = 0; jh < 4; ++jh) { \
        float4 v0 = *(const float4*)&pD0[jh << 12]; \
        float4 v1 = *(const float4*)&pD1[jh << 12]; \
        a[jh*4+0] = make_float2(v0.x, v0.y); a[jh*4+1] = make_float2(v0.z, v0.w); \
        a[jh*4+2] = make_float2(v1.x, v1.y); a[jh*4+3] = make_float2(v1.z, v1.w); } } while (0)
#define STOREP_D() do { _Pragma("unroll") for (int jh = 0; jh < 4; ++jh) { \
        *(float4*)&pD0[jh << 12] = make_float4(a[jh*4+0].x, a[jh*4+0].y, a[jh*4+1].x, a[jh*4+1].y); \
        *(float4*)&pD1[jh << 12] = make_float4(a[jh*4+2].x, a[jh*4+2].y, a[jh*4+3].x, a[jh*4+3].y); } } while (0)

    // ---- P1 (D: bits 12,13,0,1): analytic set0 state, diag0, set1 bits 12,13 ----
    {
        SETUP_D();
        {
            float2 F = make_float2(1.f, 0.f);
            #pragma unroll
            for (int bp = 2; bp < 12; ++bp) {
                int b = (t >> (bp - 2)) & 1;
                float2 f = s_U[0][13 - bp][b ? 2 : 0];
                F = cmul(F, f);
            }
            float2 g01[4], g23[4];
            #pragma unroll
            for (int j1 = 0; j1 < 2; ++j1)
                #pragma unroll
                for (int j0 = 0; j0 < 2; ++j0)
                    g01[(j1 << 1) | j0] = cmul(s_U[0][13][j0 ? 2 : 0], s_U[0][12][j1 ? 2 : 0]);
            #pragma unroll
            for (int j3 = 0; j3 < 2; ++j3)
                #pragma unroll
                for (int j2 = 0; j2 < 2; ++j2)
                    g23[(j3 << 1) | j2] = cmul(s_U[0][1][j2 ? 2 : 0], s_U[0][0][j3 ? 2 : 0]);
            float2 Fg[4];
            #pragma unroll
            for (int jl = 0; jl < 4; ++jl) Fg[jl] = cmul(F, g01[jl]);
            #pragma unroll
            for (int j = 0; j < 16; ++j) a[j] = cmul(Fg[j & 3], g23[j >> 2]);
        }
        {   // diag0, hoisted: C0 by c=j&3 (4 vals), C1 by jh=j>>2 (4 vals)
            float2 c0v[4], c1v[4];
            int tb = t << 2;
            #pragma unroll
            for (int c = 0; c < 4; ++c) { int kc = tb | c; int mc = kc ^ (kc >> 1); c0v[c] = s_C0[0][mc & 127]; }
            #pragma unroll
            for (int jh = 0; jh < 4; ++jh) { int kh = (jh << 12) | tb; int mh = kh ^ (kh >> 1); c1v[jh] = s_C1[0][(mh >> 7) & 63]; }
            #pragma unroll
            for (int j = 0; j < 16; ++j) a[j] = cmul(a[j], cmul(c0v[j & 3], c1v[j >> 2]));
        }
        GATE_BIT(2, s_U[1][1]);   // bit12 -> qubit 1
        GATE_BIT(3, s_U[1][0]);   // bit13 -> qubit 0
        STOREP_D();
    }
    __syncthreads();

    // ---- P2 (C): set1 bits 8-11 ----
    {
        SETUP_C();
        LOADP_C();
        GATE_BIT(0, s_U[1][5]); GATE_BIT(1, s_U[1][4]);
        GATE_BIT(2, s_U[1][3]); GATE_BIT(3, s_U[1][2]);
        STOREP_C();
    }
    __syncthreads();

    // ---- P3 (B): set1 bits 4-7 ----
    {
        SETUP_B();
        LOADP_B();
        GATE_BIT(0, s_U[1][9]); GATE_BIT(1, s_U[1][8]);
        GATE_BIT(2, s_U[1][7]); GATE_BIT(3, s_U[1][6]);
        STOREP_B();
    }
    __syncthreads();

    // ---- P4 (A): set1 bits 0-3, diag1, set2 bits 0-3, measure X 0-2 ----
    {
        SETUP_A();
        LOADP_A();
        GATE_BIT(0, s_U[1][13]); GATE_BIT(1, s_U[1][12]);
        GATE_BIT(2, s_U[1][11]); GATE_BIT(3, s_U[1][10]);
        {   // diag1: C1 uniform per thread, C0 per j
            int tb = t << 4; int mT = tb ^ (tb >> 1);
            float2 c1u = s_C1[1][(mT >> 7) & 63];
            #pragma unroll
            for (int j = 0; j < 16; ++j) {
                int kj = tb | j; int mj = kj ^ (kj >> 1);
                a[j] = cmul(a[j], cmul(s_C0[1][mj & 127], c1u));
            }
        }
        GATE_BIT(0, s_U[2][13]); GATE_BIT(1, s_U[2][12]);
        GATE_BIT(2, s_U[2][11]); GATE_BIT(3, s_U[2][10]);
        {
            float2 w0a = s_WE[0][0], w0b = s_WE[0][2];
            MEASW(0, (((j >> 1) & 1) ? w0b : w0a));
        }
        {
            float2 wv0 = s_WE[1][0], wv1 = s_WE[1][1], wv2 = s_WE[1][2], wv3 = s_WE[1][3];
            MEASW(1, (((j >> 2) & 1) ? ((j & 1) ? wv3 : wv2) : ((j & 1) ? wv1 : wv0)));
        }
        {
            float2 wv0 = s_WE[2][0], wv1 = s_WE[2][1], wv2 = s_WE[2][2], wv3 = s_WE[2][3];
            MEASW(2, (((j >> 3) & 1) ? (((j >> 1) & 1) ? wv3 : wv2) : (((j >> 1) & 1) ? wv1 : wv0)));
        }
        STOREP_A();
    }
    __syncthreads();

    // ---- P5 (B): set2 bits 4-7, measure X 4-6 ----
    {
        SETUP_B();
        LOADP_B();
        GATE_BIT(0, s_U[2][9]); GATE_BIT(1, s_U[2][8]);
        GATE_BIT(2, s_U[2][7]); GATE_BIT(3, s_U[2][6]);
        {
            int nlo = (t >> 3) & 1;
            float2 wa = s_WE[4][nlo], wb = s_WE[4][2 | nlo];
            MEASW(0, (((j >> 1) & 1) ? wb : wa));
        }
        {
            float2 wv0 = s_WE[5][0], wv1 = s_WE[5][1], wv2 = s_WE[5][2], wv3 = s_WE[5][3];
            MEASW(1, (((j >> 2) & 1) ? ((j & 1) ? wv3 : wv2) : ((j & 1) ? wv1 : wv0)));
        }
        {
            float2 wv0 = s_WE[6][0], wv1 = s_WE[6][1], wv2 = s_WE[6][2], wv3 = s_WE[6][3];
            MEASW(2, (((j >> 3) & 1) ? (((j >> 1) & 1) ? wv3 : wv2) : (((j >> 1) & 1) ? wv1 : wv0)));
        }
        STOREP_B();
    }
    __syncthreads();

    // ---- P6 (C): set2 bits 8-11, measure X 8-10 ----
    {
        SETUP_C();
        LOADP_C();
        GATE_BIT(0, s_U[2][5]); GATE_BIT(1, s_U[2][4]);
        GATE_BIT(2, s_U[2][3]); GATE_BIT(3, s_U[2][2]);
        {
            int nlo = (t >> 7) & 1;
            float2 wa = s_WE[8][nlo], wb = s_WE[8][2 | nlo];
            MEASW(0, (((j >> 1) & 1) ? wb : wa));
        }
        {
            float2 wv0 = s_WE[9][0], wv1 = s_WE[9][1], wv2 = s_WE[9][2], wv3 = s_WE[9][3];
            MEASW(1, (((j >> 2) & 1) ? ((j & 1) ? wv3 : wv2) : ((j & 1) ? wv1 : wv0)));
        }
        {
            float2 wv0 = s_WE[10][0], wv1 = s_WE[10][1], wv2 = s_WE[10][2], wv3 = s_WE[10][3];
            MEASW(2, (((j >> 3) & 1) ? (((j >> 1) & 1) ? wv3 : wv2) : (((j >> 1) & 1) ? wv1 : wv0)));
        }
        STOREP_C();
    }
    __syncthreads();

    // ---- P7 (D): set2 bits 12,13, measure X 12,13 ----
    {
        SETUP_D();
        LOADP_D();
        GATE_BIT(2, s_U[2][1]); GATE_BIT(3, s_U[2][0]);
        {
            int nlo = (t >> 9) & 1;
            float2 wa = s_WE[12][nlo], wb = s_WE[12][2 | nlo];
            MEASW(2, (((j >> 3) & 1) ? wb : wa));
        }
        {
            float2 wa = s_WE[13][0], wb = s_WE[13][1];
            MEASW(3, (((j >> 2) & 1) ? wb : wa));
        }
        STOREP_D();
    }
    __syncthreads();

    // ---- P8 (E: bits 2,3,7,11): measure X 3,7,11 + WZ sweep (load only) ----
    {
        int kb = (t & 3) | (((t >> 2) & 7) << 4) | (((t >> 5) & 7) << 8) | (((t >> 8) & 3) << 12);
        int exor = ((t >> 2) & 7) << 1;
        int ks[16];
        #pragma unroll
        for (int j = 0; j < 16; ++j) {
            int k = kb | ((j & 3) << 2) | (((j >> 2) & 1) << 7) | (((j >> 3) & 1) << 11);
            ks[j] = k;
            a[j] = s_amp[k ^ exor];
        }
        // WZ: hoist 4 GH (by j>>2) and 4 GL (by j&3)
        {
            float ghv[4], glv[4];
            int khb = kb >> 7, klb = kb & 127;
            #pragma unroll
            for (int q2 = 0; q2 < 4; ++q2) ghv[q2] = s_GH[khb | (q2 & 1) | ((q2 >> 1) << 4)];
            #pragma unroll
            for (int c = 0; c < 4; ++c) glv[c] = s_GL[klb | (c << 2)];
            float wzs = 0.f;
            #pragma unroll
            for (int j = 0; j < 16; ++j) {
                float prj = a[j].x*a[j].x + a[j].y*a[j].y;
                wzs += prj * (ghv[j >> 2] - 2.0f * glv[j & 3]);
            }
            acc += wzs;
            (void)ks;
        }
        {
            int nh = (t >> 2) & 1;
            float2 wa = s_WE[3][nh << 1], wb = s_WE[3][(nh << 1) | 1];
            MEASW(1, ((j & 1) ? wb : wa));
        }
        {
            float2 w7 = s_WE[7][(((t >> 5) & 1) << 1) | ((t >> 4) & 1)];
            MEASW(2, w7);
        }
        {
            float2 w11 = s_WE[11][(((t >> 8) & 1) << 1) | ((t >> 7) & 1)];
            MEASW(3, w11);
        }
    }

    // ---- block reduction ----
    #pragma unroll
    for (int off = 32; off > 0; off >>= 1)
        acc += __shfl_down(acc, off);
    if ((t & 63) == 0) s_red[t >> 6] = acc;
    __syncthreads();
    if (t == 0) {
        float s = 0.0f;
        #pragma unroll
        for (int w = 0; w < 16; ++w) s += s_red[w];
        out[n] = s;
    }
}

extern "C" void kernel_launch(void* const* d_in, const int* in_sizes, int n_in,
                              void* d_out, int out_size, void* d_ws, size_t ws_size,
                              hipStream_t stream) {
    const float* x    = (const float*)d_in[0];
    const float* psq  = (const float*)d_in[1];
    const float* p2q  = (const float*)d_in[2];
    const float* penc = (const float*)d_in[3];
    const float* pcl  = (const float*)d_in[4];
    float* out = (float*)d_out;
    pqc_kernel<<<NB, NT, 0, stream>>>(x, psq, p2q, penc, pcl, out);
}

// Round 8
// 43.066 us; speedup vs baseline: 1.0578x; 1.0578x over previous
//
#include <hip/hip_runtime.h>
#include <math.h>

#define NQ_     14
#define DIM_    16384
#define NB      256
#define NLAYERS 3
#define NPAIR   13
#define NT      1024

__device__ __forceinline__ float2 cmul(float2 a, float2 b) {
    return make_float2(a.x*b.x - a.y*b.y, a.x*b.y + a.y*b.x);
}

// SU(2) gate: u10 = -conj(u01), u11 = conj(u00) derived with free neg modifiers.
__device__ __forceinline__ void g2s(float2& a0, float2& a1, float2 u00, float2 u01) {
    float2 b0, b1;
    b0.x =  u00.x*a0.x - u00.y*a0.y + u01.x*a1.x - u01.y*a1.y;
    b0.y =  u00.x*a0.y + u00.y*a0.x + u01.x*a1.y + u01.y*a1.x;
    b1.x = -u01.x*a0.x - u01.y*a0.y + u00.x*a1.x + u00.y*a1.y;
    b1.y = -u01.x*a0.y + u01.y*a0.x + u00.x*a1.y - u00.y*a1.x;
    a0 = b0; a1 = b1;
}

#define GATE_BIT(RB, SET, Q) do { \
    float4 uu = s_U4[SET][Q]; \
    float2 u00 = make_float2(uu.x, uu.y), u01 = make_float2(uu.z, uu.w); \
    _Pragma("unroll") \
    for (int j = 0; j < 16; ++j) \
        if (!((j >> (RB)) & 1)) g2s(a[j], a[j | (1 << (RB))], u00, u01); \
} while (0)

// X/Y measurement only (Z handled by the s_GL/s_GH sweep in the final pass).
#define MEASW(RB, WEXPR) do { float xr = 0.f; \
    _Pragma("unroll") for (int j = 0; j < 16; ++j) { \
        if (!((j >> (RB)) & 1)) { \
            int j1 = j | (1 << (RB)); \
            float cr = a[j].x*a[j1].x + a[j].y*a[j1].y; \
            float ci = a[j].x*a[j1].y - a[j].y*a[j1].x; \
            float2 w = (WEXPR); \
            xr += w.x * cr - w.y * ci; \
        } } \
    acc += xr; } while (0)

__global__ __launch_bounds__(NT)
__attribute__((amdgpu_waves_per_eu(4, 4)))
void pqc_kernel(
    const float* __restrict__ x,     // (256, 28)
    const float* __restrict__ psq,   // (3, 2, 14, 3)
    const float* __restrict__ p2q,   // (3, 196)
    const float* __restrict__ penc,  // (3, 196)
    const float* __restrict__ pcl,   // (14,)
    float* __restrict__ out)         // (256,)
{
    __shared__ __align__(16) float2 s_amp[DIM_];   // 128 KiB state
    __shared__ float4 s_U4[4][NQ_];                // merged gate sets: (u00, u01); SU(2) derives rest
    __shared__ float2 s_C0[2][128];                // diag cis (layers 0,1; low 7 xor-bits)
    __shared__ float2 s_C1[2][64];                 // diag cis (layers 0,1; high bits, -S/2 folded)
    __shared__ float2 s_WE[NQ_][4];                // 2*W_bp*cis(dphi(s)), s=(k_{bp+1}<<1)|k_{bp-1}
    __shared__ float  s_GL[128];                   // gamma Z-weight, low 7 bits
    __shared__ float  s_GH[128];                   // gamma Z-weight, high 7 bits (Cg folded)
    __shared__ float  s_theta[NLAYERS][NPAIR];
    __shared__ float  s_red[16];

    const int n = blockIdx.x;
    const int t = threadIdx.x;

    // ---------- phase 1: theta + merged gate matrices ----------
    if (t < NLAYERS * NPAIR) {
        int l = t / NPAIR, p = t - l * NPAIR;
        const float* xr = x + n * 28;
        float feat = xr[2*p] * xr[2*p+2] + xr[2*p+1] * xr[2*p+3];
        int pf = 15 * p + 1;
        s_theta[l][p] = p2q[l*196 + pf] + penc[l*196 + pf] * feat;
    } else if (t >= 64 && t < 64 + 4 * NQ_) {
        int j = t - 64;
        int set = j / NQ_;
        int q = j - set * NQ_;
        auto build = [&](int l, int s, float2 Uo[4]) {
            const float* a = psq + ((l * 2 + s) * NQ_ + q) * 3;
            float phi = a[0], th = a[1], om = a[2];
            float sh, ch; sincosf(0.5f * th, &sh, &ch);
            float sa, ca; sincosf(0.5f * (phi + om), &sa, &ca);
            float sb, cb; sincosf(0.5f * (phi - om), &sb, &cb);
            Uo[0] = make_float2( ch * ca, -ch * sa);
            Uo[1] = make_float2(-sh * cb, -sh * sb);
            Uo[2] = make_float2( sh * cb, -sh * sb);
            Uo[3] = make_float2( ch * ca,  ch * sa);
        };
        float2 M[4];
        if (set == 0) {
            build(0, 0, M);
        } else if (set == 3) {
            build(2, 1, M);
        } else {
            float2 A[4], Bm[4];
            build(set, 0, A);        // second
            build(set - 1, 1, Bm);   // first
            M[0].x = A[0].x*Bm[0].x - A[0].y*Bm[0].y + A[1].x*Bm[2].x - A[1].y*Bm[2].y;
            M[0].y = A[0].x*Bm[0].y + A[0].y*Bm[0].x + A[1].x*Bm[2].y + A[1].y*Bm[2].x;
            M[1].x = A[0].x*Bm[1].x - A[0].y*Bm[1].y + A[1].x*Bm[3].x - A[1].y*Bm[3].y;
            M[1].y = A[0].x*Bm[1].y + A[0].y*Bm[1].x + A[1].x*Bm[3].y + A[1].y*Bm[3].x;
        }
        s_U4[set][q] = make_float4(M[0].x, M[0].y, M[1].x, M[1].y);
    }
    __syncthreads();

    // ---------- phase 2: diag cis tables + observable tables ----------
    if (t < 256) {
        int l = t >> 7, i = t & 127;
        float v = 0.0f;
        #pragma unroll
        for (int b = 0; b < 7; ++b)
            if ((i >> b) & 1) v += s_theta[l][12 - b];
        float sn, cs; sincosf(v, &sn, &cs);
        s_C0[l][i] = make_float2(cs, sn);
    } else if (t < 384) {
        int j = t - 256;
        int l = j >> 6, h = j & 63;
        float S = 0.0f;
        #pragma unroll
        for (int p = 0; p < NPAIR; ++p) S += s_theta[l][p];
        float v = -0.5f * S;
        #pragma unroll
        for (int b = 7; b < 13; ++b)
            if ((h >> (b - 7)) & 1) v += s_theta[l][12 - b];
        float sn, cs; sincosf(v, &sn, &cs);
        s_C1[l][h] = make_float2(cs, sn);
    } else if (t < 440) {
        // WE[bp][s] = 2 * W_bp * cis(dphi)
        int idx = t - 384, bp = idx >> 2, s = idx & 3;
        int q = 13 - bp;
        float4 uu = s_U4[3][q];
        float2 v00 = make_float2(uu.x, uu.y), v01 = make_float2(uu.z, uu.w);
        float2 v10 = make_float2(-uu.z, uu.w), v11 = make_float2(uu.x, -uu.y);
        float cz = pcl[q], cx = pcl[bp];
        float t1x = (v00.x*v01.x + v00.y*v01.y) - (v10.x*v11.x + v10.y*v11.y);
        float t1y = (v00.x*v01.y - v00.y*v01.x) - (v10.x*v11.y - v10.y*v11.x);
        float t2x = (v00.x*v11.x + v00.y*v11.y) + (v10.x*v01.x + v10.y*v01.y);
        float t2y = (v00.x*v11.y - v00.y*v11.x) + (v10.x*v01.y - v10.y*v01.x);
        float Wx = cz*t1x + cx*t2x, Wy = cz*t1y + cx*t2y;
        float tha = (bp <= 12) ? s_theta[2][12 - bp] : 0.f;
        float thb = (bp >= 1)  ? s_theta[2][13 - bp] : 0.f;
        float dphi = tha * (1.f - 2.f*((s >> 1) & 1)) + thb * (1.f - 2.f*(s & 1));
        float sn, cs; sincosf(dphi, &sn, &cs);
        s_WE[bp][s] = make_float2(2.f*(Wx*cs - Wy*sn), 2.f*(Wx*sn + Wy*cs));
    } else if (t >= 464 && t < 592) {
        // GL[i] = sum_{b<7, bit set} gamma_b
        int i = t - 464;
        float v = 0.f;
        #pragma unroll
        for (int b = 0; b < 7; ++b)
            if ((i >> b) & 1) {
                int q = 13 - b;
                float4 uu = s_U4[3][q];
                float2 v00 = make_float2(uu.x, uu.y), v10 = make_float2(-uu.z, uu.w);
                v += pcl[q] * ((v00.x*v00.x + v00.y*v00.y) - (v10.x*v10.x + v10.y*v10.y))
                   + 2.f*pcl[b] * (v00.x*v10.x + v00.y*v10.y);
            }
        s_GL[i] = v;
    } else if (t >= 592 && t < 720) {
        // GH[h] = sum_{b<7} gamma_b + sum_{b>=7} gamma_b * (1-2*bit)
        int h = t - 592;
        float v = 0.f;
        #pragma unroll
        for (int b = 0; b < 14; ++b) {
            int q = 13 - b;
            float4 uu = s_U4[3][q];
            float2 v00 = make_float2(uu.x, uu.y), v10 = make_float2(-uu.z, uu.w);
            float g = pcl[q] * ((v00.x*v00.x + v00.y*v00.y) - (v10.x*v10.x + v10.y*v10.y))
                    + 2.f*pcl[b] * (v00.x*v10.x + v00.y*v10.y);
            v += (b >= 7 && ((h >> (b - 7)) & 1)) ? -g : g;
        }
        s_GH[h] = v;
    }
    __syncthreads();

    float2 a[16];
    float acc = 0.0f;

    // ---- layouts: swizzle pre-folded to (base ^ cst) + (j<<k) forms ----
    // A (bits 0-3): addr = (t<<4) + ((2c) ^ ax), ax = (t&7)<<1
#define LOAD_A() do { const int ax = (t & 7) << 1; const int ab = t << 4; \
        _Pragma("unroll") for (int c = 0; c < 8; ++c) { \
        float4 v = *(const float4*)&s_amp[ab + ((2*c) ^ ax)]; \
        a[2*c] = make_float2(v.x, v.y); a[2*c+1] = make_float2(v.z, v.w); } } while (0)
#define STORE_A() do { const int ax = (t & 7) << 1; const int ab = t << 4; \
        _Pragma("unroll") for (int c = 0; c < 8; ++c) \
        *(float4*)&s_amp[ab + ((2*c) ^ ax)] = make_float4(a[2*c].x, a[2*c].y, a[2*c+1].x, a[2*c+1].y); } while (0)
    // B (bits 4-7): addr = (bb ^ ((j&7)<<1)) + (j<<4)
#define LOAD_B() do { const int bb = ((t >> 4) << 8) | (t & 15); _Pragma("unroll") \
        for (int j = 0; j < 16; ++j) a[j] = s_amp[(bb ^ ((j & 7) << 1)) + (j << 4)]; } while (0)
#define STORE_B() do { const int bb = ((t >> 4) << 8) | (t & 15); _Pragma("unroll") \
        for (int j = 0; j < 16; ++j) s_amp[(bb ^ ((j & 7) << 1)) + (j << 4)] = a[j]; } while (0)
    // C (bits 8-11): uniform xor, addr = bcs + (j<<8)
#define LOAD_C() do { const int bcs = ((((t >> 8) << 12) | (t & 255))) ^ (((t >> 4) & 7) << 1); \
        _Pragma("unroll") for (int j = 0; j < 16; ++j) a[j] = s_amp[bcs + (j << 8)]; } while (0)
#define STORE_C() do { const int bcs = ((((t >> 8) << 12) | (t & 255))) ^ (((t >> 4) & 7) << 1); \
        _Pragma("unroll") for (int j = 0; j < 16; ++j) s_amp[bcs + (j << 8)] = a[j]; } while (0)
    // D (bits 12,13,0,1): addr = (dbase ^ (2c)) + (jh<<12), dbase = (t<<2) ^ ((t>>2)&7)<<1
#define LOAD_D() do { const int dbase = (t << 2) ^ (((t >> 2) & 7) << 1); \
        _Pragma("unroll") for (int jh = 0; jh < 4; ++jh) \
        _Pragma("unroll") for (int c = 0; c < 2; ++c) { \
        float4 v = *(const float4*)&s_amp[(dbase ^ (2*c)) + (jh << 12)]; \
        a[jh*4+2*c] = make_float2(v.x, v.y); a[jh*4+2*c+1] = make_float2(v.z, v.w); } } while (0)
#define STORE_D() do { const int dbase = (t << 2) ^ (((t >> 2) & 7) << 1); \
        _Pragma("unroll") for (int jh = 0; jh < 4; ++jh) \
        _Pragma("unroll") for (int c = 0; c < 2; ++c) \
        *(float4*)&s_amp[(dbase ^ (2*c)) + (jh << 12)] = \
            make_float4(a[jh*4+2*c].x, a[jh*4+2*c].y, a[jh*4+2*c+1].x, a[jh*4+2*c+1].y); } while (0)

    // ---- P1 (D: bits 12,13,0,1): analytic set0 state, diag0, set1 bits 12,13 ----
    {
        {
            float2 F = make_float2(1.f, 0.f);
            #pragma unroll
            for (int bp = 2; bp < 12; ++bp) {
                int b = (t >> (bp - 2)) & 1;
                float4 uu = s_U4[0][13 - bp];
                float2 f = b ? make_float2(-uu.z, uu.w) : make_float2(uu.x, uu.y);
                F = cmul(F, f);
            }
            float4 u13 = s_U4[0][13], u12 = s_U4[0][12];
            float4 u1q = s_U4[0][1],  u0q = s_U4[0][0];
            float2 c13[2] = { make_float2(u13.x, u13.y), make_float2(-u13.z, u13.w) };
            float2 c12[2] = { make_float2(u12.x, u12.y), make_float2(-u12.z, u12.w) };
            float2 c1q[2] = { make_float2(u1q.x, u1q.y), make_float2(-u1q.z, u1q.w) };
            float2 c0q[2] = { make_float2(u0q.x, u0q.y), make_float2(-u0q.z, u0q.w) };
            float2 g01[4], g23[4];
            #pragma unroll
            for (int j1 = 0; j1 < 2; ++j1)
                #pragma unroll
                for (int j0 = 0; j0 < 2; ++j0)
                    g01[(j1 << 1) | j0] = cmul(c13[j0], c12[j1]);
            #pragma unroll
            for (int j3 = 0; j3 < 2; ++j3)
                #pragma unroll
                for (int j2 = 0; j2 < 2; ++j2)
                    g23[(j3 << 1) | j2] = cmul(c1q[j2], c0q[j3]);
            float2 Fg[4];
            #pragma unroll
            for (int jl = 0; jl < 4; ++jl) Fg[jl] = cmul(F, g01[jl]);
            #pragma unroll
            for (int j = 0; j < 16; ++j) a[j] = cmul(Fg[j & 3], g23[j >> 2]);
        }
        {   // diag0, hoisted: C0 by c=j&3 (4 vals), C1 by jh=j>>2 (4 vals)
            float2 c0v[4], c1v[4];
            int tb = t << 2;
            #pragma unroll
            for (int c = 0; c < 4; ++c) { int kc = tb | c; int mc = kc ^ (kc >> 1); c0v[c] = s_C0[0][mc & 127]; }
            #pragma unroll
            for (int jh = 0; jh < 4; ++jh) { int kh = (jh << 12) | tb; int mh = kh ^ (kh >> 1); c1v[jh] = s_C1[0][(mh >> 7) & 63]; }
            #pragma unroll
            for (int j = 0; j < 16; ++j) a[j] = cmul(a[j], cmul(c0v[j & 3], c1v[j >> 2]));
        }
        GATE_BIT(2, 1, 1);   // bit12 -> qubit 1
        GATE_BIT(3, 1, 0);   // bit13 -> qubit 0
        STORE_D();
    }
    __syncthreads();

    // ---- P2 (C): set1 bits 8-11 ----
    LOAD_C();
    GATE_BIT(0, 1, 5); GATE_BIT(1, 1, 4);
    GATE_BIT(2, 1, 3); GATE_BIT(3, 1, 2);
    STORE_C();
    __syncthreads();

    // ---- P3 (B): set1 bits 4-7 ----
    LOAD_B();
    GATE_BIT(0, 1, 9); GATE_BIT(1, 1, 8);
    GATE_BIT(2, 1, 7); GATE_BIT(3, 1, 6);
    STORE_B();
    __syncthreads();

    // ---- P4 (A): set1 bits 0-3, diag1, set2 bits 0-3, measure X 0-2 ----
    {
        LOAD_A();
        GATE_BIT(0, 1, 13); GATE_BIT(1, 1, 12);
        GATE_BIT(2, 1, 11); GATE_BIT(3, 1, 10);
        {   // diag1: C1 uniform per thread; C0 index = T0 ^ J(j) (J compile-time)
            int tb = t << 4; int mT = tb ^ (tb >> 1);
            float2 c1u = s_C1[1][(mT >> 7) & 63];
            int T0 = ((t & 1) << 3) | (((t ^ (t >> 1)) & 7) << 4);
            #pragma unroll
            for (int j = 0; j < 16; ++j) {
                int idx = T0 ^ ((j ^ (j >> 1)) & 15);
                a[j] = cmul(a[j], cmul(s_C0[1][idx], c1u));
            }
        }
        GATE_BIT(0, 2, 13); GATE_BIT(1, 2, 12);
        GATE_BIT(2, 2, 11); GATE_BIT(3, 2, 10);
        {
            float2 w0a = s_WE[0][0], w0b = s_WE[0][2];
            MEASW(0, (((j >> 1) & 1) ? w0b : w0a));
        }
        {
            float2 wv0 = s_WE[1][0], wv1 = s_WE[1][1], wv2 = s_WE[1][2], wv3 = s_WE[1][3];
            MEASW(1, (((j >> 2) & 1) ? ((j & 1) ? wv3 : wv2) : ((j & 1) ? wv1 : wv0)));
        }
        {
            float2 wv0 = s_WE[2][0], wv1 = s_WE[2][1], wv2 = s_WE[2][2], wv3 = s_WE[2][3];
            MEASW(2, (((j >> 3) & 1) ? (((j >> 1) & 1) ? wv3 : wv2) : (((j >> 1) & 1) ? wv1 : wv0)));
        }
        STORE_A();
    }
    __syncthreads();

    // ---- P5 (B): set2 bits 4-7, measure X 4-6 ----
    {
        LOAD_B();
        GATE_BIT(0, 2, 9); GATE_BIT(1, 2, 8);
        GATE_BIT(2, 2, 7); GATE_BIT(3, 2, 6);
        {
            int nlo = (t >> 3) & 1;
            float2 wa = s_WE[4][nlo], wb = s_WE[4][2 | nlo];
            MEASW(0, (((j >> 1) & 1) ? wb : wa));
        }
        {
            float2 wv0 = s_WE[5][0], wv1 = s_WE[5][1], wv2 = s_WE[5][2], wv3 = s_WE[5][3];
            MEASW(1, (((j >> 2) & 1) ? ((j & 1) ? wv3 : wv2) : ((j & 1) ? wv1 : wv0)));
        }
        {
            float2 wv0 = s_WE[6][0], wv1 = s_WE[6][1], wv2 = s_WE[6][2], wv3 = s_WE[6][3];
            MEASW(2, (((j >> 3) & 1) ? (((j >> 1) & 1) ? wv3 : wv2) : (((j >> 1) & 1) ? wv1 : wv0)));
        }
        STORE_B();
    }
    __syncthreads();

    // ---- P6 (C): set2 bits 8-11, measure X 8-10 ----
    {
        LOAD_C();
        GATE_BIT(0, 2, 5); GATE_BIT(1, 2, 4);
        GATE_BIT(2, 2, 3); GATE_BIT(3, 2, 2);
        {
            int nlo = (t >> 7) & 1;
            float2 wa = s_WE[8][nlo], wb = s_WE[8][2 | nlo];
            MEASW(0, (((j >> 1) & 1) ? wb : wa));
        }
        {
            float2 wv0 = s_WE[9][0], wv1 = s_WE[9][1], wv2 = s_WE[9][2], wv3 = s_WE[9][3];
            MEASW(1, (((j >> 2) & 1) ? ((j & 1) ? wv3 : wv2) : ((j & 1) ? wv1 : wv0)));
        }
        {
            float2 wv0 = s_WE[10][0], wv1 = s_WE[10][1], wv2 = s_WE[10][2], wv3 = s_WE[10][3];
            MEASW(2, (((j >> 3) & 1) ? (((j >> 1) & 1) ? wv3 : wv2) : (((j >> 1) & 1) ? wv1 : wv0)));
        }
        STORE_C();
    }
    __syncthreads();

    // ---- P7 (D): set2 bits 12,13, measure X 12,13 ----
    {
        LOAD_D();
        GATE_BIT(2, 2, 1); GATE_BIT(3, 2, 0);
        {
            int nlo = (t >> 9) & 1;
            float2 wa = s_WE[12][nlo], wb = s_WE[12][2 | nlo];
            MEASW(2, (((j >> 3) & 1) ? wb : wa));
        }
        {
            float2 wa = s_WE[13][0], wb = s_WE[13][1];
            MEASW(3, (((j >> 2) & 1) ? wb : wa));
        }
        STORE_D();
    }
    __syncthreads();

    // ---- P8 (E: bits 2,3,7,11): measure X 3,7,11 + WZ sweep (load only) ----
    {
        int kb = (t & 3) | (((t >> 2) & 7) << 4) | (((t >> 5) & 7) << 8) | (((t >> 8) & 3) << 12);
        int base_e = kb ^ (((t >> 2) & 7) << 1);
        #pragma unroll
        for (int j = 0; j < 16; ++j)
            a[j] = s_amp[(base_e ^ ((j & 3) << 2)) + ((((j >> 2) & 1) << 7) | (((j >> 3) & 1) << 11))];
        // WZ: hoist 4 GH (by j>>2) and 4 GL (by j&3)
        {
            float ghv[4], glv[4];
            int khb = kb >> 7, klb = kb & 127;
            #pragma unroll
            for (int q2 = 0; q2 < 4; ++q2) ghv[q2] = s_GH[khb | (q2 & 1) | ((q2 >> 1) << 4)];
            #pragma unroll
            for (int c = 0; c < 4; ++c) glv[c] = s_GL[klb | (c << 2)];
            float wzs = 0.f;
            #pragma unroll
            for (int j = 0; j < 16; ++j) {
                float prj = a[j].x*a[j].x + a[j].y*a[j].y;
                wzs += prj * (ghv[j >> 2] - 2.0f * glv[j & 3]);
            }
            acc += wzs;
        }
        {
            int nh = (t >> 2) & 1;
            float2 wa = s_WE[3][nh << 1], wb = s_WE[3][(nh << 1) | 1];
            MEASW(1, ((j & 1) ? wb : wa));
        }
        {
            float2 w7 = s_WE[7][(((t >> 5) & 1) << 1) | ((t >> 4) & 1)];
            MEASW(2, w7);
        }
        {
            float2 w11 = s_WE[11][(((t >> 8) & 1) << 1) | ((t >> 7) & 1)];
            MEASW(3, w11);
        }
    }

    // ---- block reduction ----
    #pragma unroll
    for (int off = 32; off > 0; off >>= 1)
        acc += __shfl_down(acc, off);
    if ((t & 63) == 0) s_red[t >> 6] = acc;
    __syncthreads();
    if (t == 0) {
        float s = 0.0f;
        #pragma unroll
        for (int w = 0; w < 16; ++w) s += s_red[w];
        out[n] = s;
    }
}

extern "C" void kernel_launch(void* const* d_in, const int* in_sizes, int n_in,
                              void* d_out, int out_size, void* d_ws, size_t ws_size,
                              hipStream_t stream) {
    const float* x    = (const float*)d_in[0];
    const float* psq  = (const float*)d_in[1];
    const float* p2q  = (const float*)d_in[2];
    const float* penc = (const float*)d_in[3];
    const float* pcl  = (const float*)d_in[4];
    float* out = (float*)d_out;
    pqc_kernel<<<NB, NT, 0, stream>>>(x, psq, p2q, penc, pcl, out);
}